// Round 9
// baseline (405.499 us; speedup 1.0000x reference)
//
#include <hip/hip_runtime.h>
#include <math.h>

#define HIDD 512
#define NHH 8
#define HDD 64
#define MDD 16
#define Bz 4
#define Sz 1024
#define DTf 0.1f
#define EPSf 1e-8f
#define SCALEf 0.125f  // HD^-0.5 = 1/8

typedef unsigned short ushort_t;
typedef unsigned int uint_t;

// ---- workspace layout (float2 units) ----
constexpr size_t OFF_Q    = 0;
constexpr size_t OFF_K    = OFF_Q + (size_t)Bz * NHH * Sz * MDD;   // 524288
constexpr size_t OFF_V    = OFF_K + (size_t)Bz * NHH * Sz * MDD;
constexpr size_t OFF_E    = OFF_V + (size_t)Bz * NHH * Sz * MDD;
constexpr size_t OFF_T    = OFF_E + (size_t)Bz * Sz * NHH * MDD;
constexpr size_t OFF_WOT  = OFF_T + 256;
constexpr size_t OFF_FLAG = OFF_WOT + 512 * 128;                   // 2 ints

__device__ __forceinline__ float bf2f(ushort_t u) {
  union { unsigned int i; float f; } c;
  c.i = ((unsigned int)u) << 16;
  return c.f;
}
__device__ __forceinline__ ushort_t f2bf(float f) {
  unsigned int x = __float_as_uint(f);
  unsigned int r = (x + 0x7fffu + ((x >> 16) & 1u)) >> 16;  // RNE
  return (ushort_t)r;
}
// load complex element i: bf=true -> interleaved bf16 pairs, else float2
__device__ __forceinline__ float2 ldc(const void* p, int i, bool bf) {
  if (bf) {
    ushort2 u = ((const ushort2*)p)[i];
    return make_float2(bf2f(u.x), bf2f(u.y));
  }
  return ((const float2*)p)[i];
}
__device__ __forceinline__ float ldr(const void* p, size_t i, bool bf) {
  if (bf) return bf2f(((const ushort_t*)p)[i]);
  return ((const float*)p)[i];
}

__device__ __forceinline__ float2 cmadd(float2 acc, float2 a, float2 b) {
  acc.x = fmaf(a.x, b.x, fmaf(-a.y, b.y, acc.x));
  acc.y = fmaf(a.x, b.y, fmaf(a.y, b.x, acc.y));
  return acc;
}

// ---------------------------------------------------------------------------
// KD: dtype detector (input-side dispatch; mismatched reads would NaN —
// R4/R6/R7/R8 finite proves flags matched reality).
// ---------------------------------------------------------------------------
__global__ __launch_bounds__(64) void k_detect(const uint_t* __restrict__ metric_u,
                                               const ushort_t* __restrict__ xr_u,
                                               int* __restrict__ flags) {
  if (threadIdx.x == 0) {
    flags[0] = (metric_u[0] == 0x00003F80u) ? 1 : 0;
    int cnt = 0;
    for (int i = 0; i < 256; i++) {
      unsigned e = (xr_u[i] >> 7) & 0xFFu;
      if (e >= 100u && e <= 134u) cnt++;
    }
    flags[1] = (cnt > 192) ? 1 : 0;
  }
}

// ---------------------------------------------------------------------------
// K0: T = metric @ ((1-DT)I + DT*sym)^10,  sym = 0.5*(metric + metric^H)
// ---------------------------------------------------------------------------
__global__ __launch_bounds__(256) void k_prep(const void* __restrict__ metric,
                                              const int* __restrict__ flags,
                                              float2* __restrict__ Tg) {
  __shared__ float2 mets[256], Ms[256], Ps[256];
  bool cbf = flags[0] != 0;
  int tid = threadIdx.x;
  int i = tid >> 4, j = tid & 15;
  mets[tid] = ldc(metric, tid, cbf);
  __syncthreads();
  float2 a = mets[tid];
  float2 bt = mets[j * 16 + i];
  float2 symv = make_float2(0.5f * (a.x + bt.x), 0.5f * (a.y - bt.y));
  float2 Mv = make_float2(DTf * symv.x, DTf * symv.y);
  if (i == j) Mv.x += 1.0f - DTf;
  Ms[tid] = Mv;
  Ps[tid] = Mv;
  __syncthreads();
  for (int it = 0; it < 9; it++) {  // P = M^10
    float2 acc = make_float2(0.f, 0.f);
    #pragma unroll
    for (int k = 0; k < 16; k++) acc = cmadd(acc, Ps[i * 16 + k], Ms[k * 16 + j]);
    __syncthreads();
    Ps[tid] = acc;
    __syncthreads();
  }
  float2 acc = make_float2(0.f, 0.f);
  #pragma unroll
  for (int k = 0; k < 16; k++) acc = cmadd(acc, mets[i * 16 + k], Ps[k * 16 + j]);
  Tg[tid] = acc;
}

// ---------------------------------------------------------------------------
// K0b: Wo [512,128] complex -> WoT (float2, [128,512])
// ---------------------------------------------------------------------------
__global__ __launch_bounds__(256) void k_transW(const void* __restrict__ Wo,
                                                const int* __restrict__ flags,
                                                float2* __restrict__ WoT) {
  bool cbf = flags[0] != 0;
  int idx = blockIdx.x * 256 + threadIdx.x;  // 65536 complex elements
  int o = idx >> 7, j = idx & 127;
  WoT[(size_t)j * 512 + o] = ldc(Wo, idx, cbf);
}

// ---------------------------------------------------------------------------
// K1: per-token manifold pipeline -> q,k,v  [B*NH, S, MD] complex fp32
// block = 256 threads = 64 tokens x 4 lanes
// ---------------------------------------------------------------------------
__global__ __launch_bounds__(256) void k_qkv(
    const void* __restrict__ xr, const void* __restrict__ xi,
    const void* __restrict__ Wm, const void* __restrict__ bm,
    const void* __restrict__ Wq, const void* __restrict__ bq,
    const void* __restrict__ Wk, const void* __restrict__ bk,
    const void* __restrict__ Wv, const void* __restrict__ bv,
    const float2* __restrict__ Tg, const int* __restrict__ flags,
    float2* __restrict__ qo, float2* __restrict__ ko, float2* __restrict__ vo) {
  __shared__ float2 hs[64 * 65];     // x tile (re,im), padded
  __shared__ float2 msc[64 * 17];    // exp-mapped m, padded
  __shared__ float2 wmt[64 * 16];    // Wm transposed [e][d]
  __shared__ float2 Tm[256];
  __shared__ float2 wqt[256], wkt[256], wvt[256];
  __shared__ float2 bms[16], bqs[16], bks[16], bvs[16];
  float2* msc2 = hs;  // reuse hs after phase B (barrier-protected)

  bool cbf = flags[0] != 0;
  bool xbf = flags[1] != 0;
  int tid = threadIdx.x;
  int bh = blockIdx.y;
  int s0 = blockIdx.x * 64;

  // ---- stage x tile (64 tokens x 64 dims) -> float ----
  size_t xoff = ((size_t)(((bh >> 3) * Sz) + s0)) * HIDD + (bh & 7) * HDD;
  if (xbf) {
    const ushort_t* xrb = (const ushort_t*)xr + xoff;
    const ushort_t* xib = (const ushort_t*)xi + xoff;
    #pragma unroll
    for (int it = 0; it < 4; it++) {
      int idx = tid + it * 256;
      int i = idx >> 4, e4 = idx & 15;
      ushort4 ur = ((const ushort4*)(xrb + (size_t)i * HIDD))[e4];
      ushort4 ui = ((const ushort4*)(xib + (size_t)i * HIDD))[e4];
      int e = e4 * 4;
      hs[i * 65 + e + 0] = make_float2(bf2f(ur.x), bf2f(ui.x));
      hs[i * 65 + e + 1] = make_float2(bf2f(ur.y), bf2f(ui.y));
      hs[i * 65 + e + 2] = make_float2(bf2f(ur.z), bf2f(ui.z));
      hs[i * 65 + e + 3] = make_float2(bf2f(ur.w), bf2f(ui.w));
    }
  } else {
    const float* xrb = (const float*)xr + xoff;
    const float* xib = (const float*)xi + xoff;
    #pragma unroll
    for (int it = 0; it < 4; it++) {
      int idx = tid + it * 256;
      int i = idx >> 4, e4 = idx & 15;
      float4 fr = ((const float4*)(xrb + (size_t)i * HIDD))[e4];
      float4 fi = ((const float4*)(xib + (size_t)i * HIDD))[e4];
      int e = e4 * 4;
      hs[i * 65 + e + 0] = make_float2(fr.x, fi.x);
      hs[i * 65 + e + 1] = make_float2(fr.y, fi.y);
      hs[i * 65 + e + 2] = make_float2(fr.z, fi.z);
      hs[i * 65 + e + 3] = make_float2(fr.w, fi.w);
    }
  }
  // ---- stage weights ----
  #pragma unroll
  for (int it = 0; it < 4; it++) {
    int c = tid + it * 256;          // complex index into Wm [16,64]
    int d = c >> 6, e = c & 63;
    wmt[e * 16 + d] = ldc(Wm, c, cbf);
  }
  {
    int j = tid >> 4, d = tid & 15;
    Tm[tid] = Tg[tid];
    wqt[d * 16 + j] = ldc(Wq, tid, cbf);
    wkt[d * 16 + j] = ldc(Wk, tid, cbf);
    wvt[d * 16 + j] = ldc(Wv, tid, cbf);
    if (tid < 16) {
      bms[tid] = ldc(bm, tid, cbf); bqs[tid] = ldc(bq, tid, cbf);
      bks[tid] = ldc(bk, tid, cbf); bvs[tid] = ldc(bv, tid, cbf);
    }
  }
  __syncthreads();

  int tok = tid >> 2, g = tid & 3;
  int jb = g * 4;

  // ---- phase B: m = h @ Wm^T + bm, hyperbolic exp map ----
  float2 acc[4];
  #pragma unroll
  for (int i2 = 0; i2 < 4; i2++) acc[i2] = bms[jb + i2];
  for (int e = 0; e < 64; e++) {
    float2 hv = hs[tok * 65 + e];
    #pragma unroll
    for (int i2 = 0; i2 < 4; i2++) acc[i2] = cmadd(acc[i2], hv, wmt[e * 16 + jb + i2]);
  }
  float nn = 0.f;
  #pragma unroll
  for (int i2 = 0; i2 < 4; i2++) nn += acc[i2].x * acc[i2].x + acc[i2].y * acc[i2].y;
  nn += __shfl_xor(nn, 1);
  nn += __shfl_xor(nn, 2);
  float n1 = sqrtf(nn) + EPSf;
  float sc1 = tanhf(n1) / n1;
  #pragma unroll
  for (int i2 = 0; i2 < 4; i2++)
    msc[tok * 17 + jb + i2] = make_float2(acc[i2].x * sc1, acc[i2].y * sc1);
  __syncthreads();

  // ---- phase C1: m2 = m @ T (metric+flow folded), log map ----
  float2 m2[4];
  #pragma unroll
  for (int i2 = 0; i2 < 4; i2++) m2[i2] = make_float2(0.f, 0.f);
  for (int d = 0; d < 16; d++) {
    float2 mv = msc[tok * 17 + d];
    #pragma unroll
    for (int i2 = 0; i2 < 4; i2++) m2[i2] = cmadd(m2[i2], mv, Tm[d * 16 + jb + i2]);
  }
  float nn2 = 0.f;
  #pragma unroll
  for (int i2 = 0; i2 < 4; i2++) nn2 += m2[i2].x * m2[i2].x + m2[i2].y * m2[i2].y;
  nn2 += __shfl_xor(nn2, 1);
  nn2 += __shfl_xor(nn2, 2);
  float n2 = sqrtf(nn2);
  n2 = fminf(fmaxf(n2, EPSf), 1.0f - 1e-6f);
  float fac = atanhf(n2) / n2;
  #pragma unroll
  for (int i2 = 0; i2 < 4; i2++)
    msc2[tok * 17 + jb + i2] = make_float2(m2[i2].x * fac, m2[i2].y * fac);
  __syncthreads();

  // ---- phase C2: q/k/v = m_log @ W^T + b ----
  float2 qa[4], ka[4], va[4];
  #pragma unroll
  for (int i2 = 0; i2 < 4; i2++) { qa[i2] = bqs[jb + i2]; ka[i2] = bks[jb + i2]; va[i2] = bvs[jb + i2]; }
  for (int d = 0; d < 16; d++) {
    float2 mv = msc2[tok * 17 + d];
    #pragma unroll
    for (int i2 = 0; i2 < 4; i2++) {
      qa[i2] = cmadd(qa[i2], mv, wqt[d * 16 + jb + i2]);
      ka[i2] = cmadd(ka[i2], mv, wkt[d * 16 + jb + i2]);
      va[i2] = cmadd(va[i2], mv, wvt[d * 16 + jb + i2]);
    }
  }
  size_t base = ((size_t)bh * Sz + s0 + tok) * MDD + jb;
  #pragma unroll
  for (int i2 = 0; i2 < 4; i2++) {
    qo[base + i2] = qa[i2];
    ko[base + i2] = ka[i2];
    vo[base + i2] = va[i2];
  }
}

// ---------------------------------------------------------------------------
// K2: flash-style complex attention (fp32 workspace in/out).
// block = 256 threads = 64 queries x 4 lanes; lane owns 4 complex dims
// ---------------------------------------------------------------------------
__global__ __launch_bounds__(256) void k_attn(const float2* __restrict__ qw,
                                              const float2* __restrict__ kw,
                                              const float2* __restrict__ vw,
                                              float2* __restrict__ eo) {
  __shared__ float4 kl[128 * 8];  // 128 keys x 16 complex
  __shared__ float4 vl[128 * 8];
  int tid = threadIdx.x;
  int bh = blockIdx.y;
  int b = bh >> 3, h = bh & 7;
  int ql = tid >> 2, g = tid & 3;
  int s = blockIdx.x * 64 + ql;

  const float4* qp = (const float4*)(qw + ((size_t)bh * Sz + s) * MDD);
  float4 q0 = qp[g * 2], q1 = qp[g * 2 + 1];
  float4 o0 = make_float4(0.f, 0.f, 0.f, 0.f);
  float4 o1 = make_float4(0.f, 0.f, 0.f, 0.f);
  float m_run = -INFINITY, l_run = 0.f;

  for (int t0 = 0; t0 < Sz; t0 += 128) {
    __syncthreads();
    const float4* kg = (const float4*)(kw + ((size_t)bh * Sz + t0) * MDD);
    const float4* vg = (const float4*)(vw + ((size_t)bh * Sz + t0) * MDD);
    #pragma unroll
    for (int it = 0; it < 4; it++) {
      kl[tid + it * 256] = kg[tid + it * 256];
      vl[tid + it * 256] = vg[tid + it * 256];
    }
    __syncthreads();
    #pragma unroll 4
    for (int tt = 0; tt < 128; tt++) {
      float4 kv0 = kl[tt * 8 + g * 2], kv1 = kl[tt * 8 + g * 2 + 1];
      float part = q0.x * kv0.x + q0.y * kv0.y + q0.z * kv0.z + q0.w * kv0.w
                 + q1.x * kv1.x + q1.y * kv1.y + q1.z * kv1.z + q1.w * kv1.w;
      part += __shfl_xor(part, 1);
      part += __shfl_xor(part, 2);
      float scv = part * SCALEf;
      float m_new = fmaxf(m_run, scv);
      float alpha = __expf(m_run - m_new);
      float p = __expf(scv - m_new);
      l_run = fmaf(l_run, alpha, p);
      m_run = m_new;
      float4 vv0 = vl[tt * 8 + g * 2], vv1 = vl[tt * 8 + g * 2 + 1];
      o0.x = fmaf(o0.x, alpha, p * vv0.x);
      o0.y = fmaf(o0.y, alpha, p * vv0.y);
      o0.z = fmaf(o0.z, alpha, p * vv0.z);
      o0.w = fmaf(o0.w, alpha, p * vv0.w);
      o1.x = fmaf(o1.x, alpha, p * vv1.x);
      o1.y = fmaf(o1.y, alpha, p * vv1.y);
      o1.z = fmaf(o1.z, alpha, p * vv1.z);
      o1.w = fmaf(o1.w, alpha, p * vv1.w);
    }
  }
  float inv = 1.0f / l_run;
  // expanded layout: [B, S, NH*MD] complex fp32
  float4* ep = (float4*)(eo + (((size_t)(b * Sz + s)) * NHH + h) * MDD);
  ep[g * 2]     = make_float4(o0.x * inv, o0.y * inv, o0.z * inv, o0.w * inv);
  ep[g * 2 + 1] = make_float4(o1.x * inv, o1.y * inv, o1.z * inv, o1.w * inv);
}

// ---------------------------------------------------------------------------
// K3: out = expanded @ Wo^T + bo + x.
// MODE 0: d_out = 2M float32 = REAL PART ONLY, [B,S,HID] row-major
//         (complex64 ref passed through np .astype(float32) drops imag).
// MODE 1: d_out = 4M bf16, interleaved (im,re) per complex element
//         ((re,im) interleave was ruled out in R4).
// ---------------------------------------------------------------------------
template <int MODE>
__global__ __launch_bounds__(256) void k_proj(const float2* __restrict__ ew,
                                              const float2* __restrict__ WoT,
                                              const void* __restrict__ bo,
                                              const void* __restrict__ xr,
                                              const void* __restrict__ xi,
                                              const int* __restrict__ flags,
                                              void* __restrict__ outv) {
  __shared__ float2 es[8 * 128];
  bool cbf = flags[0] != 0;
  bool xbf = flags[1] != 0;
  int tid = threadIdx.x;
  int tok0 = blockIdx.x * 8;
  #pragma unroll
  for (int it = 0; it < 4; it++) {
    int idx = tid + it * 256;
    es[idx] = ew[(size_t)tok0 * 128 + idx];
  }
  __syncthreads();
  for (int rep = 0; rep < 2; rep++) {
    int o = tid + rep * 256;
    float2 accT[8];
    #pragma unroll
    for (int t = 0; t < 8; t++) accT[t] = make_float2(0.f, 0.f);
    #pragma unroll 2
    for (int j = 0; j < 128; j++) {
      float2 w = WoT[(size_t)j * 512 + o];
      #pragma unroll
      for (int t = 0; t < 8; t++) accT[t] = cmadd(accT[t], es[t * 128 + j], w);
    }
    float2 bov = ldc(bo, o, cbf);
    #pragma unroll
    for (int t = 0; t < 8; t++) {
      size_t gt = tok0 + t;
      float rx = accT[t].x + bov.x + ldr(xr, gt * HIDD + o, xbf);
      if constexpr (MODE == 0) {
        ((float*)outv)[gt * HIDD + o] = rx;          // real part, f32
      } else {
        float ry = accT[t].y + bov.y + ldr(xi, gt * HIDD + o, xbf);
        ((ushort2*)outv)[gt * HIDD + o] = make_ushort2(f2bf(ry), f2bf(rx));
      }
    }
  }
}

// ---------------------------------------------------------------------------
extern "C" void kernel_launch(void* const* d_in, const int* in_sizes, int n_in,
                              void* d_out, int out_size, void* d_ws, size_t ws_size,
                              hipStream_t stream) {
  const void* xr     = d_in[0];
  const void* xi     = d_in[1];
  const void* Wm     = d_in[2];
  const void* bm     = d_in[3];
  const void* Wq     = d_in[4];
  const void* bq     = d_in[5];
  const void* Wk     = d_in[6];
  const void* bk     = d_in[7];
  const void* Wv     = d_in[8];
  const void* bv     = d_in[9];
  const void* metric = d_in[10];
  const void* Wo     = d_in[11];
  const void* bo     = d_in[12];

  float2* W = (float2*)d_ws;
  int* flags = (int*)(W + OFF_FLAG);

  k_detect<<<1, 64, 0, stream>>>((const uint_t*)metric, (const ushort_t*)xr, flags);
  k_prep<<<1, 256, 0, stream>>>(metric, flags, W + OFF_T);
  k_transW<<<256, 256, 0, stream>>>(Wo, flags, W + OFF_WOT);
  k_qkv<<<dim3(16, 32), 256, 0, stream>>>(xr, xi, Wm, bm, Wq, bq, Wk, bk, Wv, bv,
                                          W + OFF_T, flags,
                                          W + OFF_Q, W + OFF_K, W + OFF_V);
  k_attn<<<dim3(16, 32), 256, 0, stream>>>(W + OFF_Q, W + OFF_K, W + OFF_V, W + OFF_E);

  // out_size is the ground truth for the output format:
  //   2097152 = B*S*HID      -> float32, real part only
  //   4194304 = 2*B*S*HID    -> bf16, (im,re) interleaved
  if (out_size == Bz * Sz * HIDD) {
    k_proj<0><<<512, 256, 0, stream>>>(W + OFF_E, W + OFF_WOT, bo, xr, xi, flags, d_out);
  } else {
    k_proj<1><<<512, 256, 0, stream>>>(W + OFF_E, W + OFF_WOT, bo, xr, xi, flags, d_out);
  }
}

// Round 10
// 285.707 us; speedup vs baseline: 1.4193x; 1.4193x over previous
//
#include <hip/hip_runtime.h>
#include <math.h>

#define HIDD 512
#define NHH 8
#define HDD 64
#define MDD 16
#define Bz 4
#define Sz 1024
#define DTf 0.1f
#define EPSf 1e-8f
#define SCALEf 0.125f  // HD^-0.5 = 1/8
#define SPLITK 4

typedef unsigned short ushort_t;
typedef unsigned int uint_t;

// ---- workspace layout (float2 units) ----
constexpr size_t OFF_Q    = 0;
constexpr size_t OFF_K    = OFF_Q + (size_t)Bz * NHH * Sz * MDD;   // 524288
constexpr size_t OFF_V    = OFF_K + (size_t)Bz * NHH * Sz * MDD;
constexpr size_t OFF_E    = OFF_V + (size_t)Bz * NHH * Sz * MDD;
constexpr size_t OFF_T    = OFF_E + (size_t)Bz * Sz * NHH * MDD;
constexpr size_t OFF_WOT  = OFF_T + 256;
constexpr size_t OFF_FLAG = OFF_WOT + 512 * 128;                   // 1 float2 (2 ints)
constexpr size_t OFF_OP   = OFF_FLAG + 1;                          // [SPLITK][32768][16] float2
constexpr size_t OFF_ML   = OFF_OP + (size_t)SPLITK * 32768 * MDD; // [SPLITK][32768] float2
constexpr size_t OFF_END  = OFF_ML + (size_t)SPLITK * 32768;
constexpr size_t WS_NEEDED_BYTES = OFF_END * sizeof(float2);       // ~35.1 MB

__device__ __forceinline__ float bf2f(ushort_t u) {
  union { unsigned int i; float f; } c;
  c.i = ((unsigned int)u) << 16;
  return c.f;
}
__device__ __forceinline__ float2 ldc(const void* p, int i, bool bf) {
  if (bf) {
    ushort2 u = ((const ushort2*)p)[i];
    return make_float2(bf2f(u.x), bf2f(u.y));
  }
  return ((const float2*)p)[i];
}
__device__ __forceinline__ float ldr(const void* p, size_t i, bool bf) {
  if (bf) return bf2f(((const ushort_t*)p)[i]);
  return ((const float*)p)[i];
}
__device__ __forceinline__ float2 cmadd(float2 acc, float2 a, float2 b) {
  acc.x = fmaf(a.x, b.x, fmaf(-a.y, b.y, acc.x));
  acc.y = fmaf(a.x, b.y, fmaf(a.y, b.x, acc.y));
  return acc;
}

// ---------------------------------------------------------------------------
// KD: dtype detector — wave-parallel (old 1-thread version cost ~256 serial
// global-load latencies ≈ 15-20 us).
// ---------------------------------------------------------------------------
__global__ __launch_bounds__(64) void k_detect(const uint_t* __restrict__ metric_u,
                                               const ushort_t* __restrict__ xr_u,
                                               int* __restrict__ flags) {
  int lane = threadIdx.x;
  int cnt = 0;
  #pragma unroll
  for (int r = 0; r < 4; r++) {
    unsigned e = (xr_u[lane + r * 64] >> 7) & 0xFFu;
    if (e >= 100u && e <= 134u) cnt++;
  }
  cnt += __shfl_xor(cnt, 1);
  cnt += __shfl_xor(cnt, 2);
  cnt += __shfl_xor(cnt, 4);
  cnt += __shfl_xor(cnt, 8);
  cnt += __shfl_xor(cnt, 16);
  cnt += __shfl_xor(cnt, 32);
  if (lane == 0) {
    flags[0] = (metric_u[0] == 0x00003F80u) ? 1 : 0;
    flags[1] = (cnt > 192) ? 1 : 0;
  }
}

// ---------------------------------------------------------------------------
// K0: T = metric @ ((1-DT)I + DT*sym)^10
// ---------------------------------------------------------------------------
__global__ __launch_bounds__(256) void k_prep(const void* __restrict__ metric,
                                              const int* __restrict__ flags,
                                              float2* __restrict__ Tg) {
  __shared__ float2 mets[256], Ms[256], Ps[256];
  bool cbf = flags[0] != 0;
  int tid = threadIdx.x;
  int i = tid >> 4, j = tid & 15;
  mets[tid] = ldc(metric, tid, cbf);
  __syncthreads();
  float2 a = mets[tid];
  float2 bt = mets[j * 16 + i];
  float2 symv = make_float2(0.5f * (a.x + bt.x), 0.5f * (a.y - bt.y));
  float2 Mv = make_float2(DTf * symv.x, DTf * symv.y);
  if (i == j) Mv.x += 1.0f - DTf;
  Ms[tid] = Mv;
  Ps[tid] = Mv;
  __syncthreads();
  for (int it = 0; it < 9; it++) {
    float2 acc = make_float2(0.f, 0.f);
    #pragma unroll
    for (int k = 0; k < 16; k++) acc = cmadd(acc, Ps[i * 16 + k], Ms[k * 16 + j]);
    __syncthreads();
    Ps[tid] = acc;
    __syncthreads();
  }
  float2 acc = make_float2(0.f, 0.f);
  #pragma unroll
  for (int k = 0; k < 16; k++) acc = cmadd(acc, mets[i * 16 + k], Ps[k * 16 + j]);
  Tg[tid] = acc;
}

// ---------------------------------------------------------------------------
// K0b: Wo [512,128] complex -> WoT (float2, [128,512])
// ---------------------------------------------------------------------------
__global__ __launch_bounds__(256) void k_transW(const void* __restrict__ Wo,
                                                const int* __restrict__ flags,
                                                float2* __restrict__ WoT) {
  bool cbf = flags[0] != 0;
  int idx = blockIdx.x * 256 + threadIdx.x;
  int o = idx >> 7, j = idx & 127;
  WoT[(size_t)j * 512 + o] = ldc(Wo, idx, cbf);
}

// ---------------------------------------------------------------------------
// K1: per-token manifold pipeline -> q,k,v  [B*NH, S, MD] complex fp32
// ---------------------------------------------------------------------------
__global__ __launch_bounds__(256) void k_qkv(
    const void* __restrict__ xr, const void* __restrict__ xi,
    const void* __restrict__ Wm, const void* __restrict__ bm,
    const void* __restrict__ Wq, const void* __restrict__ bq,
    const void* __restrict__ Wk, const void* __restrict__ bk,
    const void* __restrict__ Wv, const void* __restrict__ bv,
    const float2* __restrict__ Tg, const int* __restrict__ flags,
    float2* __restrict__ qo, float2* __restrict__ ko, float2* __restrict__ vo) {
  __shared__ float2 hs[64 * 65];
  __shared__ float2 msc[64 * 17];
  __shared__ float2 wmt[64 * 16];
  __shared__ float2 Tm[256];
  __shared__ float2 wqt[256], wkt[256], wvt[256];
  __shared__ float2 bms[16], bqs[16], bks[16], bvs[16];
  float2* msc2 = hs;

  bool cbf = flags[0] != 0;
  bool xbf = flags[1] != 0;
  int tid = threadIdx.x;
  int bh = blockIdx.y;
  int s0 = blockIdx.x * 64;

  size_t xoff = ((size_t)(((bh >> 3) * Sz) + s0)) * HIDD + (bh & 7) * HDD;
  if (xbf) {
    const ushort_t* xrb = (const ushort_t*)xr + xoff;
    const ushort_t* xib = (const ushort_t*)xi + xoff;
    #pragma unroll
    for (int it = 0; it < 4; it++) {
      int idx = tid + it * 256;
      int i = idx >> 4, e4 = idx & 15;
      ushort4 ur = ((const ushort4*)(xrb + (size_t)i * HIDD))[e4];
      ushort4 ui = ((const ushort4*)(xib + (size_t)i * HIDD))[e4];
      int e = e4 * 4;
      hs[i * 65 + e + 0] = make_float2(bf2f(ur.x), bf2f(ui.x));
      hs[i * 65 + e + 1] = make_float2(bf2f(ur.y), bf2f(ui.y));
      hs[i * 65 + e + 2] = make_float2(bf2f(ur.z), bf2f(ui.z));
      hs[i * 65 + e + 3] = make_float2(bf2f(ur.w), bf2f(ui.w));
    }
  } else {
    const float* xrb = (const float*)xr + xoff;
    const float* xib = (const float*)xi + xoff;
    #pragma unroll
    for (int it = 0; it < 4; it++) {
      int idx = tid + it * 256;
      int i = idx >> 4, e4 = idx & 15;
      float4 fr = ((const float4*)(xrb + (size_t)i * HIDD))[e4];
      float4 fi = ((const float4*)(xib + (size_t)i * HIDD))[e4];
      int e = e4 * 4;
      hs[i * 65 + e + 0] = make_float2(fr.x, fi.x);
      hs[i * 65 + e + 1] = make_float2(fr.y, fi.y);
      hs[i * 65 + e + 2] = make_float2(fr.z, fi.z);
      hs[i * 65 + e + 3] = make_float2(fr.w, fi.w);
    }
  }
  #pragma unroll
  for (int it = 0; it < 4; it++) {
    int c = tid + it * 256;
    int d = c >> 6, e = c & 63;
    wmt[e * 16 + d] = ldc(Wm, c, cbf);
  }
  {
    int j = tid >> 4, d = tid & 15;
    Tm[tid] = Tg[tid];
    wqt[d * 16 + j] = ldc(Wq, tid, cbf);
    wkt[d * 16 + j] = ldc(Wk, tid, cbf);
    wvt[d * 16 + j] = ldc(Wv, tid, cbf);
    if (tid < 16) {
      bms[tid] = ldc(bm, tid, cbf); bqs[tid] = ldc(bq, tid, cbf);
      bks[tid] = ldc(bk, tid, cbf); bvs[tid] = ldc(bv, tid, cbf);
    }
  }
  __syncthreads();

  int tok = tid >> 2, g = tid & 3;
  int jb = g * 4;

  float2 acc[4];
  #pragma unroll
  for (int i2 = 0; i2 < 4; i2++) acc[i2] = bms[jb + i2];
  for (int e = 0; e < 64; e++) {
    float2 hv = hs[tok * 65 + e];
    #pragma unroll
    for (int i2 = 0; i2 < 4; i2++) acc[i2] = cmadd(acc[i2], hv, wmt[e * 16 + jb + i2]);
  }
  float nn = 0.f;
  #pragma unroll
  for (int i2 = 0; i2 < 4; i2++) nn += acc[i2].x * acc[i2].x + acc[i2].y * acc[i2].y;
  nn += __shfl_xor(nn, 1);
  nn += __shfl_xor(nn, 2);
  float n1 = sqrtf(nn) + EPSf;
  float sc1 = tanhf(n1) / n1;
  #pragma unroll
  for (int i2 = 0; i2 < 4; i2++)
    msc[tok * 17 + jb + i2] = make_float2(acc[i2].x * sc1, acc[i2].y * sc1);
  __syncthreads();

  float2 m2[4];
  #pragma unroll
  for (int i2 = 0; i2 < 4; i2++) m2[i2] = make_float2(0.f, 0.f);
  for (int d = 0; d < 16; d++) {
    float2 mv = msc[tok * 17 + d];
    #pragma unroll
    for (int i2 = 0; i2 < 4; i2++) m2[i2] = cmadd(m2[i2], mv, Tm[d * 16 + jb + i2]);
  }
  float nn2 = 0.f;
  #pragma unroll
  for (int i2 = 0; i2 < 4; i2++) nn2 += m2[i2].x * m2[i2].x + m2[i2].y * m2[i2].y;
  nn2 += __shfl_xor(nn2, 1);
  nn2 += __shfl_xor(nn2, 2);
  float n2 = sqrtf(nn2);
  n2 = fminf(fmaxf(n2, EPSf), 1.0f - 1e-6f);
  float fac = atanhf(n2) / n2;
  #pragma unroll
  for (int i2 = 0; i2 < 4; i2++)
    msc2[tok * 17 + jb + i2] = make_float2(m2[i2].x * fac, m2[i2].y * fac);
  __syncthreads();

  float2 qa[4], ka[4], va[4];
  #pragma unroll
  for (int i2 = 0; i2 < 4; i2++) { qa[i2] = bqs[jb + i2]; ka[i2] = bks[jb + i2]; va[i2] = bvs[jb + i2]; }
  for (int d = 0; d < 16; d++) {
    float2 mv = msc2[tok * 17 + d];
    #pragma unroll
    for (int i2 = 0; i2 < 4; i2++) {
      qa[i2] = cmadd(qa[i2], mv, wqt[d * 16 + jb + i2]);
      ka[i2] = cmadd(ka[i2], mv, wkt[d * 16 + jb + i2]);
      va[i2] = cmadd(va[i2], mv, wvt[d * 16 + jb + i2]);
    }
  }
  size_t base = ((size_t)bh * Sz + s0 + tok) * MDD + jb;
  #pragma unroll
  for (int i2 = 0; i2 < 4; i2++) {
    qo[base + i2] = qa[i2];
    ko[base + i2] = ka[i2];
    vo[base + i2] = va[i2];
  }
}

// ---------------------------------------------------------------------------
// K2a: split-K flash attention. grid (16, 32, SPLITK); block = 64 q x 4 lanes.
// Each block covers 256 keys; partial (m, l, unnormalized o) -> workspace.
// 2-key unrolled inner loop to double ILP on the online-softmax serial chain.
// ---------------------------------------------------------------------------
__global__ __launch_bounds__(256) void k_attn_sk(const float2* __restrict__ qw,
                                                 const float2* __restrict__ kw,
                                                 const float2* __restrict__ vw,
                                                 float2* __restrict__ opart,
                                                 float2* __restrict__ mlpart) {
  __shared__ float4 kl[64 * 8];  // 64 keys x 16 complex = 8 KB
  __shared__ float4 vl[64 * 8];
  int tid = threadIdx.x;
  int bh = blockIdx.y;
  int sp = blockIdx.z;
  int ql = tid >> 2, g = tid & 3;
  int s = blockIdx.x * 64 + ql;

  const float4* qp = (const float4*)(qw + ((size_t)bh * Sz + s) * MDD);
  float4 q0 = qp[g * 2], q1 = qp[g * 2 + 1];
  float4 o0 = make_float4(0.f, 0.f, 0.f, 0.f);
  float4 o1 = make_float4(0.f, 0.f, 0.f, 0.f);
  float m_run = -INFINITY, l_run = 0.f;

  int t_begin = sp * (Sz / SPLITK);
  for (int t0 = t_begin; t0 < t_begin + Sz / SPLITK; t0 += 64) {
    __syncthreads();
    const float4* kg = (const float4*)(kw + ((size_t)bh * Sz + t0) * MDD);
    const float4* vg = (const float4*)(vw + ((size_t)bh * Sz + t0) * MDD);
    kl[tid] = kg[tid]; kl[tid + 256] = kg[tid + 256];
    vl[tid] = vg[tid]; vl[tid + 256] = vg[tid + 256];
    __syncthreads();
    #pragma unroll 4
    for (int tt = 0; tt < 64; tt += 2) {
      float4 ka0 = kl[tt * 8 + g * 2],       ka1 = kl[tt * 8 + g * 2 + 1];
      float4 kb0 = kl[(tt + 1) * 8 + g * 2], kb1 = kl[(tt + 1) * 8 + g * 2 + 1];
      float p1 = q0.x * ka0.x + q0.y * ka0.y + q0.z * ka0.z + q0.w * ka0.w
               + q1.x * ka1.x + q1.y * ka1.y + q1.z * ka1.z + q1.w * ka1.w;
      float p2 = q0.x * kb0.x + q0.y * kb0.y + q0.z * kb0.z + q0.w * kb0.w
               + q1.x * kb1.x + q1.y * kb1.y + q1.z * kb1.z + q1.w * kb1.w;
      p1 += __shfl_xor(p1, 1);
      p2 += __shfl_xor(p2, 1);
      p1 += __shfl_xor(p1, 2);
      p2 += __shfl_xor(p2, 2);
      float s1 = p1 * SCALEf, s2 = p2 * SCALEf;
      float m_new = fmaxf(m_run, fmaxf(s1, s2));
      float alpha = __expf(m_run - m_new);
      float e1 = __expf(s1 - m_new);
      float e2 = __expf(s2 - m_new);
      l_run = fmaf(l_run, alpha, e1 + e2);
      m_run = m_new;
      float4 va0 = vl[tt * 8 + g * 2],       va1 = vl[tt * 8 + g * 2 + 1];
      float4 vb0 = vl[(tt + 1) * 8 + g * 2], vb1 = vl[(tt + 1) * 8 + g * 2 + 1];
      o0.x = fmaf(o0.x, alpha, fmaf(e1, va0.x, e2 * vb0.x));
      o0.y = fmaf(o0.y, alpha, fmaf(e1, va0.y, e2 * vb0.y));
      o0.z = fmaf(o0.z, alpha, fmaf(e1, va0.z, e2 * vb0.z));
      o0.w = fmaf(o0.w, alpha, fmaf(e1, va0.w, e2 * vb0.w));
      o1.x = fmaf(o1.x, alpha, fmaf(e1, va1.x, e2 * vb1.x));
      o1.y = fmaf(o1.y, alpha, fmaf(e1, va1.y, e2 * vb1.y));
      o1.z = fmaf(o1.z, alpha, fmaf(e1, va1.z, e2 * vb1.z));
      o1.w = fmaf(o1.w, alpha, fmaf(e1, va1.w, e2 * vb1.w));
    }
  }
  size_t qidx = (size_t)bh * Sz + s;
  float4* op = (float4*)(opart + ((size_t)sp * 32768 + qidx) * MDD);
  op[g * 2]     = o0;   // unnormalized partial
  op[g * 2 + 1] = o1;
  if (g == 0) mlpart[(size_t)sp * 32768 + qidx] = make_float2(m_run, l_run);
}

// ---------------------------------------------------------------------------
// K2b: combine SPLITK partials -> expanded [B,S,NH*MD] complex fp32
// ---------------------------------------------------------------------------
__global__ __launch_bounds__(256) void k_comb(const float2* __restrict__ opart,
                                              const float2* __restrict__ mlpart,
                                              float2* __restrict__ eo) {
  int tid = threadIdx.x;
  int bh = blockIdx.y;
  int b = bh >> 3, h = bh & 7;
  int ql = tid >> 2, g = tid & 3;
  int s = blockIdx.x * 64 + ql;
  size_t qidx = (size_t)bh * Sz + s;

  float2 ml[SPLITK];
  float M = -INFINITY;
  #pragma unroll
  for (int i = 0; i < SPLITK; i++) {
    ml[i] = mlpart[(size_t)i * 32768 + qidx];
    M = fmaxf(M, ml[i].x);
  }
  float L = 0.f, w[SPLITK];
  #pragma unroll
  for (int i = 0; i < SPLITK; i++) {
    w[i] = __expf(ml[i].x - M);
    L = fmaf(w[i], ml[i].y, L);
  }
  float inv = 1.0f / L;
  float4 o0 = make_float4(0.f, 0.f, 0.f, 0.f);
  float4 o1 = make_float4(0.f, 0.f, 0.f, 0.f);
  #pragma unroll
  for (int i = 0; i < SPLITK; i++) {
    const float4* op = (const float4*)(opart + ((size_t)i * 32768 + qidx) * MDD);
    float4 a = op[g * 2], bb = op[g * 2 + 1];
    o0.x = fmaf(w[i], a.x, o0.x);  o0.y = fmaf(w[i], a.y, o0.y);
    o0.z = fmaf(w[i], a.z, o0.z);  o0.w = fmaf(w[i], a.w, o0.w);
    o1.x = fmaf(w[i], bb.x, o1.x); o1.y = fmaf(w[i], bb.y, o1.y);
    o1.z = fmaf(w[i], bb.z, o1.z); o1.w = fmaf(w[i], bb.w, o1.w);
  }
  float4* ep = (float4*)(eo + (((size_t)(b * Sz + s)) * NHH + h) * MDD);
  ep[g * 2]     = make_float4(o0.x * inv, o0.y * inv, o0.z * inv, o0.w * inv);
  ep[g * 2 + 1] = make_float4(o1.x * inv, o1.y * inv, o1.z * inv, o1.w * inv);
}

// ---------------------------------------------------------------------------
// K2 (fallback, no split): original flash attention — used only if ws_size
// can't hold the split-K partials.
// ---------------------------------------------------------------------------
__global__ __launch_bounds__(256) void k_attn_full(const float2* __restrict__ qw,
                                                   const float2* __restrict__ kw,
                                                   const float2* __restrict__ vw,
                                                   float2* __restrict__ eo) {
  __shared__ float4 kl[128 * 8];
  __shared__ float4 vl[128 * 8];
  int tid = threadIdx.x;
  int bh = blockIdx.y;
  int b = bh >> 3, h = bh & 7;
  int ql = tid >> 2, g = tid & 3;
  int s = blockIdx.x * 64 + ql;

  const float4* qp = (const float4*)(qw + ((size_t)bh * Sz + s) * MDD);
  float4 q0 = qp[g * 2], q1 = qp[g * 2 + 1];
  float4 o0 = make_float4(0.f, 0.f, 0.f, 0.f);
  float4 o1 = make_float4(0.f, 0.f, 0.f, 0.f);
  float m_run = -INFINITY, l_run = 0.f;

  for (int t0 = 0; t0 < Sz; t0 += 128) {
    __syncthreads();
    const float4* kg = (const float4*)(kw + ((size_t)bh * Sz + t0) * MDD);
    const float4* vg = (const float4*)(vw + ((size_t)bh * Sz + t0) * MDD);
    #pragma unroll
    for (int it = 0; it < 4; it++) {
      kl[tid + it * 256] = kg[tid + it * 256];
      vl[tid + it * 256] = vg[tid + it * 256];
    }
    __syncthreads();
    #pragma unroll 4
    for (int tt = 0; tt < 128; tt++) {
      float4 kv0 = kl[tt * 8 + g * 2], kv1 = kl[tt * 8 + g * 2 + 1];
      float part = q0.x * kv0.x + q0.y * kv0.y + q0.z * kv0.z + q0.w * kv0.w
                 + q1.x * kv1.x + q1.y * kv1.y + q1.z * kv1.z + q1.w * kv1.w;
      part += __shfl_xor(part, 1);
      part += __shfl_xor(part, 2);
      float scv = part * SCALEf;
      float m_new = fmaxf(m_run, scv);
      float alpha = __expf(m_run - m_new);
      float p = __expf(scv - m_new);
      l_run = fmaf(l_run, alpha, p);
      m_run = m_new;
      float4 vv0 = vl[tt * 8 + g * 2], vv1 = vl[tt * 8 + g * 2 + 1];
      o0.x = fmaf(o0.x, alpha, p * vv0.x);
      o0.y = fmaf(o0.y, alpha, p * vv0.y);
      o0.z = fmaf(o0.z, alpha, p * vv0.z);
      o0.w = fmaf(o0.w, alpha, p * vv0.w);
      o1.x = fmaf(o1.x, alpha, p * vv1.x);
      o1.y = fmaf(o1.y, alpha, p * vv1.y);
      o1.z = fmaf(o1.z, alpha, p * vv1.z);
      o1.w = fmaf(o1.w, alpha, p * vv1.w);
    }
  }
  float inv = 1.0f / l_run;
  float4* ep = (float4*)(eo + (((size_t)(b * Sz + s)) * NHH + h) * MDD);
  ep[g * 2]     = make_float4(o0.x * inv, o0.y * inv, o0.z * inv, o0.w * inv);
  ep[g * 2 + 1] = make_float4(o1.x * inv, o1.y * inv, o1.z * inv, o1.w * inv);
}

// ---------------------------------------------------------------------------
// K3: out = expanded @ Wo^T + bo + x.
// MODE 0 (verified R9): d_out = 2M float32 = REAL PART, [B,S,HID].
// MODE 1: bf16 (im,re) interleave — kept for robustness.
// ---------------------------------------------------------------------------
__device__ __forceinline__ ushort_t f2bf(float f) {
  unsigned int x = __float_as_uint(f);
  unsigned int r = (x + 0x7fffu + ((x >> 16) & 1u)) >> 16;
  return (ushort_t)r;
}
template <int MODE>
__global__ __launch_bounds__(256) void k_proj(const float2* __restrict__ ew,
                                              const float2* __restrict__ WoT,
                                              const void* __restrict__ bo,
                                              const void* __restrict__ xr,
                                              const void* __restrict__ xi,
                                              const int* __restrict__ flags,
                                              void* __restrict__ outv) {
  __shared__ float2 es[8 * 128];
  bool cbf = flags[0] != 0;
  bool xbf = flags[1] != 0;
  int tid = threadIdx.x;
  int tok0 = blockIdx.x * 8;
  #pragma unroll
  for (int it = 0; it < 4; it++) {
    int idx = tid + it * 256;
    es[idx] = ew[(size_t)tok0 * 128 + idx];
  }
  __syncthreads();
  for (int rep = 0; rep < 2; rep++) {
    int o = tid + rep * 256;
    float2 accT[8];
    #pragma unroll
    for (int t = 0; t < 8; t++) accT[t] = make_float2(0.f, 0.f);
    #pragma unroll 2
    for (int j = 0; j < 128; j++) {
      float2 w = WoT[(size_t)j * 512 + o];
      #pragma unroll
      for (int t = 0; t < 8; t++) accT[t] = cmadd(accT[t], es[t * 128 + j], w);
    }
    float2 bov = ldc(bo, o, cbf);
    #pragma unroll
    for (int t = 0; t < 8; t++) {
      size_t gt = tok0 + t;
      float rx = accT[t].x + bov.x + ldr(xr, gt * HIDD + o, xbf);
      if constexpr (MODE == 0) {
        ((float*)outv)[gt * HIDD + o] = rx;
      } else {
        float ry = accT[t].y + bov.y + ldr(xi, gt * HIDD + o, xbf);
        ((ushort2*)outv)[gt * HIDD + o] = make_ushort2(f2bf(ry), f2bf(rx));
      }
    }
  }
}

// ---------------------------------------------------------------------------
extern "C" void kernel_launch(void* const* d_in, const int* in_sizes, int n_in,
                              void* d_out, int out_size, void* d_ws, size_t ws_size,
                              hipStream_t stream) {
  const void* xr     = d_in[0];
  const void* xi     = d_in[1];
  const void* Wm     = d_in[2];
  const void* bm     = d_in[3];
  const void* Wq     = d_in[4];
  const void* bq     = d_in[5];
  const void* Wk     = d_in[6];
  const void* bk     = d_in[7];
  const void* Wv     = d_in[8];
  const void* bv     = d_in[9];
  const void* metric = d_in[10];
  const void* Wo     = d_in[11];
  const void* bo     = d_in[12];

  float2* W = (float2*)d_ws;
  int* flags = (int*)(W + OFF_FLAG);

  k_detect<<<1, 64, 0, stream>>>((const uint_t*)metric, (const ushort_t*)xr, flags);
  k_prep<<<1, 256, 0, stream>>>(metric, flags, W + OFF_T);
  k_transW<<<256, 256, 0, stream>>>(Wo, flags, W + OFF_WOT);
  k_qkv<<<dim3(16, 32), 256, 0, stream>>>(xr, xi, Wm, bm, Wq, bq, Wk, bk, Wv, bv,
                                          W + OFF_T, flags,
                                          W + OFF_Q, W + OFF_K, W + OFF_V);
  if (ws_size >= WS_NEEDED_BYTES) {
    k_attn_sk<<<dim3(16, 32, SPLITK), 256, 0, stream>>>(W + OFF_Q, W + OFF_K, W + OFF_V,
                                                        W + OFF_OP, W + OFF_ML);
    k_comb<<<dim3(16, 32), 256, 0, stream>>>(W + OFF_OP, W + OFF_ML, W + OFF_E);
  } else {
    k_attn_full<<<dim3(16, 32), 256, 0, stream>>>(W + OFF_Q, W + OFF_K, W + OFF_V, W + OFF_E);
  }
  if (out_size == Bz * Sz * HIDD) {
    k_proj<0><<<512, 256, 0, stream>>>(W + OFF_E, W + OFF_WOT, bo, xr, xi, flags, d_out);
  } else {
    k_proj<1><<<512, 256, 0, stream>>>(W + OFF_E, W + OFF_WOT, bo, xr, xi, flags, d_out);
  }
}

// Round 11
// 179.589 us; speedup vs baseline: 2.2579x; 1.5909x over previous
//
#include <hip/hip_runtime.h>
#include <math.h>

#define HIDD 512
#define NHH 8
#define HDD 64
#define MDD 16
#define Bz 4
#define Sz 1024
#define DTf 0.1f
#define EPSf 1e-8f
#define SCALEf 0.125f  // HD^-0.5 = 1/8

typedef unsigned short ushort_t;
typedef unsigned int uint_t;

typedef __attribute__((ext_vector_type(8))) short bf16x8;
typedef __attribute__((ext_vector_type(4))) float f32x4;

// ---- workspace layout (float2 units) ----
constexpr size_t OFF_QB   = 0;                       // Qbf  [32][1024][32] bf16 = 2 MB
constexpr size_t OFF_KB   = OFF_QB + 262144;         // Kbf  same
constexpr size_t OFF_VT   = OFF_KB + 262144;         // VTbf [32][32][1024] bf16
constexpr size_t OFF_E    = OFF_VT + 262144;         // E [B,S,NH*MD] float2 = 4 MB
constexpr size_t OFF_T    = OFF_E + (size_t)Bz * Sz * NHH * MDD;
constexpr size_t OFF_WOT  = OFF_T + 256;
constexpr size_t OFF_FLAG = OFF_WOT + 512 * 128;

__device__ __forceinline__ float bf2f(ushort_t u) {
  union { unsigned int i; float f; } c;
  c.i = ((unsigned int)u) << 16;
  return c.f;
}
__device__ __forceinline__ ushort_t f2bf(float f) {
  unsigned int x = __float_as_uint(f);
  unsigned int r = (x + 0x7fffu + ((x >> 16) & 1u)) >> 16;  // RNE
  return (ushort_t)r;
}
__device__ __forceinline__ float2 ldc(const void* p, int i, bool bf) {
  if (bf) {
    ushort2 u = ((const ushort2*)p)[i];
    return make_float2(bf2f(u.x), bf2f(u.y));
  }
  return ((const float2*)p)[i];
}
__device__ __forceinline__ float ldr(const void* p, size_t i, bool bf) {
  if (bf) return bf2f(((const ushort_t*)p)[i]);
  return ((const float*)p)[i];
}
__device__ __forceinline__ float2 cmadd(float2 acc, float2 a, float2 b) {
  acc.x = fmaf(a.x, b.x, fmaf(-a.y, b.y, acc.x));
  acc.y = fmaf(a.x, b.y, fmaf(a.y, b.x, acc.y));
  return acc;
}

// ---------------------------------------------------------------------------
// K-SETUP (fused detect + prep + transW): block 0 = flags + T matrix,
// blocks 1..256 = Wo transpose. cbf computed locally per block (no dependency).
// ---------------------------------------------------------------------------
__global__ __launch_bounds__(256) void k_setup(const void* __restrict__ metric,
                                               const ushort_t* __restrict__ xr_u,
                                               const void* __restrict__ Wo,
                                               int* __restrict__ flags,
                                               float2* __restrict__ Tg,
                                               float2* __restrict__ WoT) {
  __shared__ float2 mets[256], Ms[256], Ps2[256];
  __shared__ int votes[4];
  const uint_t* mu = (const uint_t*)metric;
  bool cbf = (mu[0] == 0x00003F80u);
  int tid = threadIdx.x;
  if (blockIdx.x == 0) {
    // flags
    unsigned e = (xr_u[tid] >> 7) & 0xFFu;
    unsigned long long bal = __ballot(e >= 100u && e <= 134u);
    if ((tid & 63) == 0) votes[tid >> 6] = (int)__popcll(bal);
    __syncthreads();
    if (tid == 0) {
      int c = votes[0] + votes[1] + votes[2] + votes[3];
      flags[0] = cbf ? 1 : 0;
      flags[1] = (c > 192) ? 1 : 0;
    }
    // prep: T = metric @ ((1-DT)I + DT*sym)^10
    int i = tid >> 4, j = tid & 15;
    mets[tid] = ldc(metric, tid, cbf);
    __syncthreads();
    float2 a = mets[tid];
    float2 bt = mets[j * 16 + i];
    float2 symv = make_float2(0.5f * (a.x + bt.x), 0.5f * (a.y - bt.y));
    float2 Mv = make_float2(DTf * symv.x, DTf * symv.y);
    if (i == j) Mv.x += 1.0f - DTf;
    Ms[tid] = Mv;
    Ps2[tid] = Mv;
    __syncthreads();
    for (int it = 0; it < 9; it++) {
      float2 acc = make_float2(0.f, 0.f);
      #pragma unroll
      for (int k = 0; k < 16; k++) acc = cmadd(acc, Ps2[i * 16 + k], Ms[k * 16 + j]);
      __syncthreads();
      Ps2[tid] = acc;
      __syncthreads();
    }
    float2 acc = make_float2(0.f, 0.f);
    #pragma unroll
    for (int k = 0; k < 16; k++) acc = cmadd(acc, mets[i * 16 + k], Ps2[k * 16 + j]);
    Tg[tid] = acc;
  } else {
    int idx = (blockIdx.x - 1) * 256 + tid;  // 65536 complex elements
    int o = idx >> 7, j = idx & 127;
    WoT[(size_t)j * 512 + o] = ldc(Wo, idx, cbf);
  }
}

// ---------------------------------------------------------------------------
// K1: manifold pipeline -> bf16 MFMA operands: Qbf (scaled), Kbf, VT-bf
// ---------------------------------------------------------------------------
__global__ __launch_bounds__(256) void k_qkv(
    const void* __restrict__ xr, const void* __restrict__ xi,
    const void* __restrict__ Wm, const void* __restrict__ bm,
    const void* __restrict__ Wq, const void* __restrict__ bq,
    const void* __restrict__ Wk, const void* __restrict__ bk,
    const void* __restrict__ Wv, const void* __restrict__ bv,
    const float2* __restrict__ Tg, const int* __restrict__ flags,
    ushort_t* __restrict__ Qb, ushort_t* __restrict__ Kb,
    ushort_t* __restrict__ VTb) {
  __shared__ float2 hs[64 * 65];
  __shared__ float2 msc[64 * 17];
  __shared__ float2 wmt[64 * 16];
  __shared__ float2 Tm[256];
  __shared__ float2 wqt[256], wkt[256], wvt[256];
  __shared__ float2 bms[16], bqs[16], bks[16], bvs[16];
  float2* msc2 = hs;

  bool cbf = flags[0] != 0;
  bool xbf = flags[1] != 0;
  int tid = threadIdx.x;
  int bh = blockIdx.y;
  int s0 = blockIdx.x * 64;

  size_t xoff = ((size_t)(((bh >> 3) * Sz) + s0)) * HIDD + (bh & 7) * HDD;
  if (xbf) {
    const ushort_t* xrb = (const ushort_t*)xr + xoff;
    const ushort_t* xib = (const ushort_t*)xi + xoff;
    #pragma unroll
    for (int it = 0; it < 4; it++) {
      int idx = tid + it * 256;
      int i = idx >> 4, e4 = idx & 15;
      ushort4 ur = ((const ushort4*)(xrb + (size_t)i * HIDD))[e4];
      ushort4 ui = ((const ushort4*)(xib + (size_t)i * HIDD))[e4];
      int e = e4 * 4;
      hs[i * 65 + e + 0] = make_float2(bf2f(ur.x), bf2f(ui.x));
      hs[i * 65 + e + 1] = make_float2(bf2f(ur.y), bf2f(ui.y));
      hs[i * 65 + e + 2] = make_float2(bf2f(ur.z), bf2f(ui.z));
      hs[i * 65 + e + 3] = make_float2(bf2f(ur.w), bf2f(ui.w));
    }
  } else {
    const float* xrb = (const float*)xr + xoff;
    const float* xib = (const float*)xi + xoff;
    #pragma unroll
    for (int it = 0; it < 4; it++) {
      int idx = tid + it * 256;
      int i = idx >> 4, e4 = idx & 15;
      float4 fr = ((const float4*)(xrb + (size_t)i * HIDD))[e4];
      float4 fi = ((const float4*)(xib + (size_t)i * HIDD))[e4];
      int e = e4 * 4;
      hs[i * 65 + e + 0] = make_float2(fr.x, fi.x);
      hs[i * 65 + e + 1] = make_float2(fr.y, fi.y);
      hs[i * 65 + e + 2] = make_float2(fr.z, fi.z);
      hs[i * 65 + e + 3] = make_float2(fr.w, fi.w);
    }
  }
  #pragma unroll
  for (int it = 0; it < 4; it++) {
    int c = tid + it * 256;
    int d = c >> 6, e = c & 63;
    wmt[e * 16 + d] = ldc(Wm, c, cbf);
  }
  {
    int j = tid >> 4, d = tid & 15;
    Tm[tid] = Tg[tid];
    wqt[d * 16 + j] = ldc(Wq, tid, cbf);
    wkt[d * 16 + j] = ldc(Wk, tid, cbf);
    wvt[d * 16 + j] = ldc(Wv, tid, cbf);
    if (tid < 16) {
      bms[tid] = ldc(bm, tid, cbf); bqs[tid] = ldc(bq, tid, cbf);
      bks[tid] = ldc(bk, tid, cbf); bvs[tid] = ldc(bv, tid, cbf);
    }
  }
  __syncthreads();

  int tok = tid >> 2, g = tid & 3;
  int jb = g * 4;

  float2 acc[4];
  #pragma unroll
  for (int i2 = 0; i2 < 4; i2++) acc[i2] = bms[jb + i2];
  for (int e = 0; e < 64; e++) {
    float2 hv = hs[tok * 65 + e];
    #pragma unroll
    for (int i2 = 0; i2 < 4; i2++) acc[i2] = cmadd(acc[i2], hv, wmt[e * 16 + jb + i2]);
  }
  float nn = 0.f;
  #pragma unroll
  for (int i2 = 0; i2 < 4; i2++) nn += acc[i2].x * acc[i2].x + acc[i2].y * acc[i2].y;
  nn += __shfl_xor(nn, 1);
  nn += __shfl_xor(nn, 2);
  float n1 = sqrtf(nn) + EPSf;
  float sc1 = tanhf(n1) / n1;
  #pragma unroll
  for (int i2 = 0; i2 < 4; i2++)
    msc[tok * 17 + jb + i2] = make_float2(acc[i2].x * sc1, acc[i2].y * sc1);
  __syncthreads();

  float2 m2[4];
  #pragma unroll
  for (int i2 = 0; i2 < 4; i2++) m2[i2] = make_float2(0.f, 0.f);
  for (int d = 0; d < 16; d++) {
    float2 mv = msc[tok * 17 + d];
    #pragma unroll
    for (int i2 = 0; i2 < 4; i2++) m2[i2] = cmadd(m2[i2], mv, Tm[d * 16 + jb + i2]);
  }
  float nn2 = 0.f;
  #pragma unroll
  for (int i2 = 0; i2 < 4; i2++) nn2 += m2[i2].x * m2[i2].x + m2[i2].y * m2[i2].y;
  nn2 += __shfl_xor(nn2, 1);
  nn2 += __shfl_xor(nn2, 2);
  float n2 = sqrtf(nn2);
  n2 = fminf(fmaxf(n2, EPSf), 1.0f - 1e-6f);
  float fac = atanhf(n2) / n2;
  #pragma unroll
  for (int i2 = 0; i2 < 4; i2++)
    msc2[tok * 17 + jb + i2] = make_float2(m2[i2].x * fac, m2[i2].y * fac);
  __syncthreads();

  float2 qa[4], ka[4], va[4];
  #pragma unroll
  for (int i2 = 0; i2 < 4; i2++) { qa[i2] = bqs[jb + i2]; ka[i2] = bks[jb + i2]; va[i2] = bvs[jb + i2]; }
  for (int d = 0; d < 16; d++) {
    float2 mv = msc2[tok * 17 + d];
    #pragma unroll
    for (int i2 = 0; i2 < 4; i2++) {
      qa[i2] = cmadd(qa[i2], mv, wqt[d * 16 + jb + i2]);
      ka[i2] = cmadd(ka[i2], mv, wkt[d * 16 + jb + i2]);
      va[i2] = cmadd(va[i2], mv, wvt[d * 16 + jb + i2]);
    }
  }
  // ---- pack to bf16 operands ----
  int s = s0 + tok;
  uint_t qp[4], kp[4];
  #pragma unroll
  for (int i2 = 0; i2 < 4; i2++) {
    qp[i2] = (uint_t)f2bf(qa[i2].x * SCALEf) | ((uint_t)f2bf(qa[i2].y * SCALEf) << 16);
    kp[i2] = (uint_t)f2bf(ka[i2].x) | ((uint_t)f2bf(ka[i2].y) << 16);
  }
  size_t rowbase = ((size_t)bh * Sz + s) * 32 + (size_t)g * 8;  // ushort idx
  *(uint4*)(Qb + rowbase) = make_uint4(qp[0], qp[1], qp[2], qp[3]);
  *(uint4*)(Kb + rowbase) = make_uint4(kp[0], kp[1], kp[2], kp[3]);
  size_t vtb = (size_t)bh * 32 * Sz;
  #pragma unroll
  for (int i2 = 0; i2 < 4; i2++) {
    int d = (jb + i2) * 2;
    VTb[vtb + (size_t)d * Sz + s]       = f2bf(va[i2].x);
    VTb[vtb + (size_t)(d + 1) * Sz + s] = f2bf(va[i2].y);
  }
}

// ---------------------------------------------------------------------------
// K2: MFMA flash attention. grid (16, 32); block = 4 waves; wave = 16 queries.
// S^T = K·Q^T via mfma_16x16x32_bf16 (scores per query live in one lane col);
// online softmax; P -> A-frag via wave-private LDS; O += P·V via 2 MFMAs.
// Verified layouts (learn_hip m89/m91/m92/m120): A/B frag: row=lane&15,
// k=quad*8+j contiguous; C/D: col=lane&15, row=quad*4+reg.
// ---------------------------------------------------------------------------
__global__ __launch_bounds__(256) void k_attn_mf(const ushort_t* __restrict__ Qb,
                                                 const ushort_t* __restrict__ Kb,
                                                 const ushort_t* __restrict__ VTb,
                                                 float* __restrict__ ef) {
  __shared__ ushort_t Ks[128 * 88];   // K chunk rows, stride 88 (16B-aligned, 2-way)
  __shared__ ushort_t VTs[32 * 152];  // V^T chunk rows, stride 152
  __shared__ ushort_t Ps[4 * 16 * 40];// per-wave P buffer, stride 40
  int tid = threadIdx.x;
  int w = tid >> 6, lane = tid & 63;
  int n = lane & 15, qd = lane >> 4;
  int bh = blockIdx.y;
  int qb = blockIdx.x * 64 + w * 16;

  const ushort_t* Qh = Qb + (size_t)bh * Sz * 32;
  const ushort_t* Kh = Kb + (size_t)bh * Sz * 32;
  const ushort_t* VTh = VTb + (size_t)bh * 32 * Sz;

  bf16x8 qf = *(const bf16x8*)(Qh + (size_t)(qb + n) * 32 + qd * 8);

  f32x4 o0 = {0.f, 0.f, 0.f, 0.f}, o1 = {0.f, 0.f, 0.f, 0.f};
  float m_run = -INFINITY, l_run = 0.f;
  ushort_t* Pw = Ps + w * 16 * 40;

  for (int kc = 0; kc < Sz; kc += 128) {
    __syncthreads();
    {
      int row = tid >> 1, half = tid & 1;
      const uint4* sk = (const uint4*)(Kh + (size_t)(kc + row) * 32 + half * 16);
      uint4 a = sk[0], b2 = sk[1];
      *(uint4*)(Ks + row * 88 + half * 16) = a;
      *(uint4*)(Ks + row * 88 + half * 16 + 8) = b2;
      int d = tid >> 3, seg = tid & 7;
      const uint4* sv = (const uint4*)(VTh + (size_t)d * Sz + kc + seg * 16);
      uint4 c = sv[0], e2 = sv[1];
      *(uint4*)(VTs + d * 152 + seg * 16) = c;
      *(uint4*)(VTs + d * 152 + seg * 16 + 8) = e2;
    }
    __syncthreads();
    #pragma unroll
    for (int st = 0; st < 4; st++) {
      int kb = st * 32;
      bf16x8 ka0 = *(const bf16x8*)(Ks + (kb + n) * 88 + qd * 8);
      bf16x8 ka1 = *(const bf16x8*)(Ks + (kb + 16 + n) * 88 + qd * 8);
      f32x4 z = {0.f, 0.f, 0.f, 0.f};
      f32x4 st0 = __builtin_amdgcn_mfma_f32_16x16x32_bf16(ka0, qf, z, 0, 0, 0);
      f32x4 st1 = __builtin_amdgcn_mfma_f32_16x16x32_bf16(ka1, qf, z, 0, 0, 0);
      // online softmax over this query's 32 scores (lane column)
      float mt = fmaxf(fmaxf(fmaxf(st0[0], st0[1]), fmaxf(st0[2], st0[3])),
                       fmaxf(fmaxf(st1[0], st1[1]), fmaxf(st1[2], st1[3])));
      mt = fmaxf(mt, __shfl_xor(mt, 16));
      mt = fmaxf(mt, __shfl_xor(mt, 32));
      float mnew = fmaxf(m_run, mt);
      float alpha = __expf(m_run - mnew);
      float p0[4], p1[4];
      #pragma unroll
      for (int r = 0; r < 4; r++) {
        p0[r] = __expf(st0[r] - mnew);
        p1[r] = __expf(st1[r] - mnew);
      }
      float ls = (p0[0] + p0[1]) + (p0[2] + p0[3])
               + (p1[0] + p1[1]) + (p1[2] + p1[3]);
      ls += __shfl_xor(ls, 16);
      ls += __shfl_xor(ls, 32);
      l_run = fmaf(l_run, alpha, ls);
      m_run = mnew;
      // P^T (C-layout) -> P[q][32k] bf16 in wave-private LDS
      #pragma unroll
      for (int r = 0; r < 4; r++) {
        Pw[n * 40 + qd * 4 + r]      = f2bf(p0[r]);
        Pw[n * 40 + 16 + qd * 4 + r] = f2bf(p1[r]);
      }
      bf16x8 pa = *(const bf16x8*)(Pw + n * 40 + qd * 8);  // A-frag of P
      bf16x8 vb0 = *(const bf16x8*)(VTs + n * 152 + kb + qd * 8);
      bf16x8 vb1 = *(const bf16x8*)(VTs + (n + 16) * 152 + kb + qd * 8);
      float ar0 = __shfl(alpha, qd * 4 + 0);
      float ar1 = __shfl(alpha, qd * 4 + 1);
      float ar2 = __shfl(alpha, qd * 4 + 2);
      float ar3 = __shfl(alpha, qd * 4 + 3);
      f32x4 oo0, oo1;
      oo0[0] = o0[0] * ar0; oo0[1] = o0[1] * ar1; oo0[2] = o0[2] * ar2; oo0[3] = o0[3] * ar3;
      oo1[0] = o1[0] * ar0; oo1[1] = o1[1] * ar1; oo1[2] = o1[2] * ar2; oo1[3] = o1[3] * ar3;
      o0 = __builtin_amdgcn_mfma_f32_16x16x32_bf16(pa, vb0, oo0, 0, 0, 0);
      o1 = __builtin_amdgcn_mfma_f32_16x16x32_bf16(pa, vb1, oo1, 0, 0, 0);
    }
  }
  // epilogue: normalize rows, write E [B,S,NH*MD] (float, interleaved re/im)
  int b = bh >> 3, h = bh & 7;
  #pragma unroll
  for (int r = 0; r < 4; r++) {
    float li = __shfl(l_run, qd * 4 + r);
    float inv = 1.0f / li;
    int tok = qb + qd * 4 + r;
    float* ep = ef + (((size_t)(b * Sz + tok)) * NHH + h) * 32;
    ep[n]      = o0[r] * inv;
    ep[16 + n] = o1[r] * inv;
  }
}

// ---------------------------------------------------------------------------
// K3: out = expanded @ Wo^T + bo + x.  MODE 0 (verified): f32 real part.
// ---------------------------------------------------------------------------
template <int MODE>
__global__ __launch_bounds__(256) void k_proj(const float2* __restrict__ ew,
                                              const float2* __restrict__ WoT,
                                              const void* __restrict__ bo,
                                              const void* __restrict__ xr,
                                              const void* __restrict__ xi,
                                              const int* __restrict__ flags,
                                              void* __restrict__ outv) {
  __shared__ float2 es[8 * 128];
  bool cbf = flags[0] != 0;
  bool xbf = flags[1] != 0;
  int tid = threadIdx.x;
  int tok0 = blockIdx.x * 8;
  #pragma unroll
  for (int it = 0; it < 4; it++) {
    int idx = tid + it * 256;
    es[idx] = ew[(size_t)tok0 * 128 + idx];
  }
  __syncthreads();
  for (int rep = 0; rep < 2; rep++) {
    int o = tid + rep * 256;
    float2 accT[8];
    #pragma unroll
    for (int t = 0; t < 8; t++) accT[t] = make_float2(0.f, 0.f);
    #pragma unroll 2
    for (int j = 0; j < 128; j++) {
      float2 wv = WoT[(size_t)j * 512 + o];
      #pragma unroll
      for (int t = 0; t < 8; t++) accT[t] = cmadd(accT[t], es[t * 128 + j], wv);
    }
    float2 bov = ldc(bo, o, cbf);
    #pragma unroll
    for (int t = 0; t < 8; t++) {
      size_t gt = tok0 + t;
      float rx = accT[t].x + bov.x + ldr(xr, gt * HIDD + o, xbf);
      if constexpr (MODE == 0) {
        ((float*)outv)[gt * HIDD + o] = rx;
      } else {
        float ry = accT[t].y + bov.y + ldr(xi, gt * HIDD + o, xbf);
        ((ushort2*)outv)[gt * HIDD + o] = make_ushort2(f2bf(ry), f2bf(rx));
      }
    }
  }
}

// ---------------------------------------------------------------------------
extern "C" void kernel_launch(void* const* d_in, const int* in_sizes, int n_in,
                              void* d_out, int out_size, void* d_ws, size_t ws_size,
                              hipStream_t stream) {
  const void* xr     = d_in[0];
  const void* xi     = d_in[1];
  const void* Wm     = d_in[2];
  const void* bm     = d_in[3];
  const void* Wq     = d_in[4];
  const void* bq     = d_in[5];
  const void* Wk     = d_in[6];
  const void* bk     = d_in[7];
  const void* Wv     = d_in[8];
  const void* bv     = d_in[9];
  const void* metric = d_in[10];
  const void* Wo     = d_in[11];
  const void* bo     = d_in[12];

  float2* W = (float2*)d_ws;
  int* flags = (int*)(W + OFF_FLAG);
  ushort_t* Qb  = (ushort_t*)(W + OFF_QB);
  ushort_t* Kb  = (ushort_t*)(W + OFF_KB);
  ushort_t* VTb = (ushort_t*)(W + OFF_VT);

  k_setup<<<257, 256, 0, stream>>>(metric, (const ushort_t*)xr, Wo, flags,
                                   W + OFF_T, W + OFF_WOT);
  k_qkv<<<dim3(16, 32), 256, 0, stream>>>(xr, xi, Wm, bm, Wq, bq, Wk, bk, Wv, bv,
                                          W + OFF_T, flags, Qb, Kb, VTb);
  k_attn_mf<<<dim3(16, 32), 256, 0, stream>>>(Qb, Kb, VTb, (float*)(W + OFF_E));
  if (out_size == Bz * Sz * HIDD) {
    k_proj<0><<<512, 256, 0, stream>>>(W + OFF_E, W + OFF_WOT, bo, xr, xi, flags, d_out);
  } else {
    k_proj<1><<<512, 256, 0, stream>>>(W + OFF_E, W + OFF_WOT, bo, xr, xi, flags, d_out);
  }
}

// Round 13
// 160.188 us; speedup vs baseline: 2.5314x; 1.1211x over previous
//
#include <hip/hip_runtime.h>
#include <math.h>

#define HIDD 512
#define NHH 8
#define HDD 64
#define MDD 16
#define Bz 4
#define Sz 1024
#define DTf 0.1f
#define EPSf 1e-8f
#define SCALEf 0.125f  // HD^-0.5 = 1/8

typedef unsigned short ushort_t;
typedef unsigned int uint_t;

typedef __attribute__((ext_vector_type(8))) short bf16x8;
typedef __attribute__((ext_vector_type(4))) float f32x4;

// ---- workspace layout (float2 units) ----
constexpr size_t OFF_QB   = 0;                       // Qbf  [32][1024][32] bf16 = 2 MB
constexpr size_t OFF_KB   = OFF_QB + 262144;         // Kbf  same
constexpr size_t OFF_VT   = OFF_KB + 262144;         // VTbf [32][32][1024] bf16
constexpr size_t OFF_E    = OFF_VT + 262144;         // E [B,S,NH*MD] float2 = 4 MB
constexpr size_t OFF_T    = OFF_E + (size_t)Bz * Sz * NHH * MDD;
constexpr size_t OFF_WOT  = OFF_T + 256;
constexpr size_t OFF_FLAG = OFF_WOT + 512 * 128;

__device__ __forceinline__ float bf2f(ushort_t u) {
  union { unsigned int i; float f; } c;
  c.i = ((unsigned int)u) << 16;
  return c.f;
}
__device__ __forceinline__ ushort_t f2bf(float f) {
  unsigned int x = __float_as_uint(f);
  unsigned int r = (x + 0x7fffu + ((x >> 16) & 1u)) >> 16;  // RNE
  return (ushort_t)r;
}
__device__ __forceinline__ float2 ldc(const void* p, int i, bool bf) {
  if (bf) {
    ushort2 u = ((const ushort2*)p)[i];
    return make_float2(bf2f(u.x), bf2f(u.y));
  }
  return ((const float2*)p)[i];
}
__device__ __forceinline__ float ldr(const void* p, size_t i, bool bf) {
  if (bf) return bf2f(((const ushort_t*)p)[i]);
  return ((const float*)p)[i];
}
__device__ __forceinline__ float2 cmadd(float2 acc, float2 a, float2 b) {
  acc.x = fmaf(a.x, b.x, fmaf(-a.y, b.y, acc.x));
  acc.y = fmaf(a.x, b.y, fmaf(a.y, b.x, acc.y));
  return acc;
}

// ---------------------------------------------------------------------------
// K-SETUP (fused detect + prep + transW): block 0 = flags + T matrix,
// blocks 1..256 = Wo transpose. (R11-proven, unchanged.)
// ---------------------------------------------------------------------------
__global__ __launch_bounds__(256) void k_setup(const void* __restrict__ metric,
                                               const ushort_t* __restrict__ xr_u,
                                               const void* __restrict__ Wo,
                                               int* __restrict__ flags,
                                               float2* __restrict__ Tg,
                                               float2* __restrict__ WoT) {
  __shared__ float2 mets[256], Ms[256], Ps2[256];
  __shared__ int votes[4];
  const uint_t* mu = (const uint_t*)metric;
  bool cbf = (mu[0] == 0x00003F80u);
  int tid = threadIdx.x;
  if (blockIdx.x == 0) {
    unsigned e = (xr_u[tid] >> 7) & 0xFFu;
    unsigned long long bal = __ballot(e >= 100u && e <= 134u);
    if ((tid & 63) == 0) votes[tid >> 6] = (int)__popcll(bal);
    __syncthreads();
    if (tid == 0) {
      int c = votes[0] + votes[1] + votes[2] + votes[3];
      flags[0] = cbf ? 1 : 0;
      flags[1] = (c > 192) ? 1 : 0;
    }
    int i = tid >> 4, j = tid & 15;
    mets[tid] = ldc(metric, tid, cbf);
    __syncthreads();
    float2 a = mets[tid];
    float2 bt = mets[j * 16 + i];
    float2 symv = make_float2(0.5f * (a.x + bt.x), 0.5f * (a.y - bt.y));
    float2 Mv = make_float2(DTf * symv.x, DTf * symv.y);
    if (i == j) Mv.x += 1.0f - DTf;
    Ms[tid] = Mv;
    Ps2[tid] = Mv;
    __syncthreads();
    for (int it = 0; it < 9; it++) {
      float2 acc = make_float2(0.f, 0.f);
      #pragma unroll
      for (int k = 0; k < 16; k++) acc = cmadd(acc, Ps2[i * 16 + k], Ms[k * 16 + j]);
      __syncthreads();
      Ps2[tid] = acc;
      __syncthreads();
    }
    float2 acc = make_float2(0.f, 0.f);
    #pragma unroll
    for (int k = 0; k < 16; k++) acc = cmadd(acc, mets[i * 16 + k], Ps2[k * 16 + j]);
    Tg[tid] = acc;
  } else {
    int idx = (blockIdx.x - 1) * 256 + tid;  // 65536 complex elements
    int o = idx >> 7, j = idx & 127;
    WoT[(size_t)j * 512 + o] = ldc(Wo, idx, cbf);
  }
}

// ---------------------------------------------------------------------------
// K1: manifold pipeline -> bf16 MFMA operands: Qbf (scaled), Kbf, VT-bf
// (R11-proven, unchanged.)
// ---------------------------------------------------------------------------
__global__ __launch_bounds__(256) void k_qkv(
    const void* __restrict__ xr, const void* __restrict__ xi,
    const void* __restrict__ Wm, const void* __restrict__ bm,
    const void* __restrict__ Wq, const void* __restrict__ bq,
    const void* __restrict__ Wk, const void* __restrict__ bk,
    const void* __restrict__ Wv, const void* __restrict__ bv,
    const float2* __restrict__ Tg, const int* __restrict__ flags,
    ushort_t* __restrict__ Qb, ushort_t* __restrict__ Kb,
    ushort_t* __restrict__ VTb) {
  __shared__ float2 hs[64 * 65];
  __shared__ float2 msc[64 * 17];
  __shared__ float2 wmt[64 * 16];
  __shared__ float2 Tm[256];
  __shared__ float2 wqt[256], wkt[256], wvt[256];
  __shared__ float2 bms[16], bqs[16], bks[16], bvs[16];
  float2* msc2 = hs;

  bool cbf = flags[0] != 0;
  bool xbf = flags[1] != 0;
  int tid = threadIdx.x;
  int bh = blockIdx.y;
  int s0 = blockIdx.x * 64;

  size_t xoff = ((size_t)(((bh >> 3) * Sz) + s0)) * HIDD + (bh & 7) * HDD;
  if (xbf) {
    const ushort_t* xrb = (const ushort_t*)xr + xoff;
    const ushort_t* xib = (const ushort_t*)xi + xoff;
    #pragma unroll
    for (int it = 0; it < 4; it++) {
      int idx = tid + it * 256;
      int i = idx >> 4, e4 = idx & 15;
      ushort4 ur = ((const ushort4*)(xrb + (size_t)i * HIDD))[e4];
      ushort4 ui = ((const ushort4*)(xib + (size_t)i * HIDD))[e4];
      int e = e4 * 4;
      hs[i * 65 + e + 0] = make_float2(bf2f(ur.x), bf2f(ui.x));
      hs[i * 65 + e + 1] = make_float2(bf2f(ur.y), bf2f(ui.y));
      hs[i * 65 + e + 2] = make_float2(bf2f(ur.z), bf2f(ui.z));
      hs[i * 65 + e + 3] = make_float2(bf2f(ur.w), bf2f(ui.w));
    }
  } else {
    const float* xrb = (const float*)xr + xoff;
    const float* xib = (const float*)xi + xoff;
    #pragma unroll
    for (int it = 0; it < 4; it++) {
      int idx = tid + it * 256;
      int i = idx >> 4, e4 = idx & 15;
      float4 fr = ((const float4*)(xrb + (size_t)i * HIDD))[e4];
      float4 fi = ((const float4*)(xib + (size_t)i * HIDD))[e4];
      int e = e4 * 4;
      hs[i * 65 + e + 0] = make_float2(fr.x, fi.x);
      hs[i * 65 + e + 1] = make_float2(fr.y, fi.y);
      hs[i * 65 + e + 2] = make_float2(fr.z, fi.z);
      hs[i * 65 + e + 3] = make_float2(fr.w, fi.w);
    }
  }
  #pragma unroll
  for (int it = 0; it < 4; it++) {
    int c = tid + it * 256;
    int d = c >> 6, e = c & 63;
    wmt[e * 16 + d] = ldc(Wm, c, cbf);
  }
  {
    int j = tid >> 4, d = tid & 15;
    Tm[tid] = Tg[tid];
    wqt[d * 16 + j] = ldc(Wq, tid, cbf);
    wkt[d * 16 + j] = ldc(Wk, tid, cbf);
    wvt[d * 16 + j] = ldc(Wv, tid, cbf);
    if (tid < 16) {
      bms[tid] = ldc(bm, tid, cbf); bqs[tid] = ldc(bq, tid, cbf);
      bks[tid] = ldc(bk, tid, cbf); bvs[tid] = ldc(bv, tid, cbf);
    }
  }
  __syncthreads();

  int tok = tid >> 2, g = tid & 3;
  int jb = g * 4;

  float2 acc[4];
  #pragma unroll
  for (int i2 = 0; i2 < 4; i2++) acc[i2] = bms[jb + i2];
  for (int e = 0; e < 64; e++) {
    float2 hv = hs[tok * 65 + e];
    #pragma unroll
    for (int i2 = 0; i2 < 4; i2++) acc[i2] = cmadd(acc[i2], hv, wmt[e * 16 + jb + i2]);
  }
  float nn = 0.f;
  #pragma unroll
  for (int i2 = 0; i2 < 4; i2++) nn += acc[i2].x * acc[i2].x + acc[i2].y * acc[i2].y;
  nn += __shfl_xor(nn, 1);
  nn += __shfl_xor(nn, 2);
  float n1 = sqrtf(nn) + EPSf;
  float sc1 = tanhf(n1) / n1;
  #pragma unroll
  for (int i2 = 0; i2 < 4; i2++)
    msc[tok * 17 + jb + i2] = make_float2(acc[i2].x * sc1, acc[i2].y * sc1);
  __syncthreads();

  float2 m2[4];
  #pragma unroll
  for (int i2 = 0; i2 < 4; i2++) m2[i2] = make_float2(0.f, 0.f);
  for (int d = 0; d < 16; d++) {
    float2 mv = msc[tok * 17 + d];
    #pragma unroll
    for (int i2 = 0; i2 < 4; i2++) m2[i2] = cmadd(m2[i2], mv, Tm[d * 16 + jb + i2]);
  }
  float nn2 = 0.f;
  #pragma unroll
  for (int i2 = 0; i2 < 4; i2++) nn2 += m2[i2].x * m2[i2].x + m2[i2].y * m2[i2].y;
  nn2 += __shfl_xor(nn2, 1);
  nn2 += __shfl_xor(nn2, 2);
  float n2 = sqrtf(nn2);
  n2 = fminf(fmaxf(n2, EPSf), 1.0f - 1e-6f);
  float fac = atanhf(n2) / n2;
  #pragma unroll
  for (int i2 = 0; i2 < 4; i2++)
    msc2[tok * 17 + jb + i2] = make_float2(m2[i2].x * fac, m2[i2].y * fac);
  __syncthreads();

  float2 qa[4], ka[4], va[4];
  #pragma unroll
  for (int i2 = 0; i2 < 4; i2++) { qa[i2] = bqs[jb + i2]; ka[i2] = bks[jb + i2]; va[i2] = bvs[jb + i2]; }
  for (int d = 0; d < 16; d++) {
    float2 mv = msc2[tok * 17 + d];
    #pragma unroll
    for (int i2 = 0; i2 < 4; i2++) {
      qa[i2] = cmadd(qa[i2], mv, wqt[d * 16 + jb + i2]);
      ka[i2] = cmadd(ka[i2], mv, wkt[d * 16 + jb + i2]);
      va[i2] = cmadd(va[i2], mv, wvt[d * 16 + jb + i2]);
    }
  }
  // ---- pack to bf16 operands ----
  int s = s0 + tok;
  uint_t qp[4], kp[4];
  #pragma unroll
  for (int i2 = 0; i2 < 4; i2++) {
    qp[i2] = (uint_t)f2bf(qa[i2].x * SCALEf) | ((uint_t)f2bf(qa[i2].y * SCALEf) << 16);
    kp[i2] = (uint_t)f2bf(ka[i2].x) | ((uint_t)f2bf(ka[i2].y) << 16);
  }
  size_t rowbase = ((size_t)bh * Sz + s) * 32 + (size_t)g * 8;  // ushort idx
  *(uint4*)(Qb + rowbase) = make_uint4(qp[0], qp[1], qp[2], qp[3]);
  *(uint4*)(Kb + rowbase) = make_uint4(kp[0], kp[1], kp[2], kp[3]);
  size_t vtb = (size_t)bh * 32 * Sz;
  #pragma unroll
  for (int i2 = 0; i2 < 4; i2++) {
    int d = (jb + i2) * 2;
    VTb[vtb + (size_t)d * Sz + s]       = f2bf(va[i2].x);
    VTb[vtb + (size_t)(d + 1) * Sz + s] = f2bf(va[i2].y);
  }
}

// ---------------------------------------------------------------------------
// K2: MFMA flash attention (R11-proven, unchanged). Writes float E.
// ---------------------------------------------------------------------------
__global__ __launch_bounds__(256) void k_attn_mf(const ushort_t* __restrict__ Qb,
                                                 const ushort_t* __restrict__ Kb,
                                                 const ushort_t* __restrict__ VTb,
                                                 float* __restrict__ ef) {
  __shared__ ushort_t Ks[128 * 88];
  __shared__ ushort_t VTs[32 * 152];
  __shared__ ushort_t Ps[4 * 16 * 40];
  int tid = threadIdx.x;
  int w = tid >> 6, lane = tid & 63;
  int n = lane & 15, qd = lane >> 4;
  int bh = blockIdx.y;
  int qb = blockIdx.x * 64 + w * 16;

  const ushort_t* Qh = Qb + (size_t)bh * Sz * 32;
  const ushort_t* Kh = Kb + (size_t)bh * Sz * 32;
  const ushort_t* VTh = VTb + (size_t)bh * 32 * Sz;

  bf16x8 qf = *(const bf16x8*)(Qh + (size_t)(qb + n) * 32 + qd * 8);

  f32x4 o0 = {0.f, 0.f, 0.f, 0.f}, o1 = {0.f, 0.f, 0.f, 0.f};
  float m_run = -INFINITY, l_run = 0.f;
  ushort_t* Pw = Ps + w * 16 * 40;

  for (int kc = 0; kc < Sz; kc += 128) {
    __syncthreads();
    {
      int row = tid >> 1, half = tid & 1;
      const uint4* sk = (const uint4*)(Kh + (size_t)(kc + row) * 32 + half * 16);
      uint4 a = sk[0], b2 = sk[1];
      *(uint4*)(Ks + row * 88 + half * 16) = a;
      *(uint4*)(Ks + row * 88 + half * 16 + 8) = b2;
      int d = tid >> 3, seg = tid & 7;
      const uint4* sv = (const uint4*)(VTh + (size_t)d * Sz + kc + seg * 16);
      uint4 c = sv[0], e2 = sv[1];
      *(uint4*)(VTs + d * 152 + seg * 16) = c;
      *(uint4*)(VTs + d * 152 + seg * 16 + 8) = e2;
    }
    __syncthreads();
    #pragma unroll
    for (int st = 0; st < 4; st++) {
      int kb = st * 32;
      bf16x8 ka0 = *(const bf16x8*)(Ks + (kb + n) * 88 + qd * 8);
      bf16x8 ka1 = *(const bf16x8*)(Ks + (kb + 16 + n) * 88 + qd * 8);
      f32x4 z = {0.f, 0.f, 0.f, 0.f};
      f32x4 st0 = __builtin_amdgcn_mfma_f32_16x16x32_bf16(ka0, qf, z, 0, 0, 0);
      f32x4 st1 = __builtin_amdgcn_mfma_f32_16x16x32_bf16(ka1, qf, z, 0, 0, 0);
      float mt = fmaxf(fmaxf(fmaxf(st0[0], st0[1]), fmaxf(st0[2], st0[3])),
                       fmaxf(fmaxf(st1[0], st1[1]), fmaxf(st1[2], st1[3])));
      mt = fmaxf(mt, __shfl_xor(mt, 16));
      mt = fmaxf(mt, __shfl_xor(mt, 32));
      float mnew = fmaxf(m_run, mt);
      float alpha = __expf(m_run - mnew);
      float p0[4], p1[4];
      #pragma unroll
      for (int r = 0; r < 4; r++) {
        p0[r] = __expf(st0[r] - mnew);
        p1[r] = __expf(st1[r] - mnew);
      }
      float ls = (p0[0] + p0[1]) + (p0[2] + p0[3])
               + (p1[0] + p1[1]) + (p1[2] + p1[3]);
      ls += __shfl_xor(ls, 16);
      ls += __shfl_xor(ls, 32);
      l_run = fmaf(l_run, alpha, ls);
      m_run = mnew;
      #pragma unroll
      for (int r = 0; r < 4; r++) {
        Pw[n * 40 + qd * 4 + r]      = f2bf(p0[r]);
        Pw[n * 40 + 16 + qd * 4 + r] = f2bf(p1[r]);
      }
      bf16x8 pa = *(const bf16x8*)(Pw + n * 40 + qd * 8);
      bf16x8 vb0 = *(const bf16x8*)(VTs + n * 152 + kb + qd * 8);
      bf16x8 vb1 = *(const bf16x8*)(VTs + (n + 16) * 152 + kb + qd * 8);
      float ar0 = __shfl(alpha, qd * 4 + 0);
      float ar1 = __shfl(alpha, qd * 4 + 1);
      float ar2 = __shfl(alpha, qd * 4 + 2);
      float ar3 = __shfl(alpha, qd * 4 + 3);
      f32x4 oo0, oo1;
      oo0[0] = o0[0] * ar0; oo0[1] = o0[1] * ar1; oo0[2] = o0[2] * ar2; oo0[3] = o0[3] * ar3;
      oo1[0] = o1[0] * ar0; oo1[1] = o1[1] * ar1; oo1[2] = o1[2] * ar2; oo1[3] = o1[3] * ar3;
      o0 = __builtin_amdgcn_mfma_f32_16x16x32_bf16(pa, vb0, oo0, 0, 0, 0);
      o1 = __builtin_amdgcn_mfma_f32_16x16x32_bf16(pa, vb1, oo1, 0, 0, 0);
    }
  }
  int b = bh >> 3, h = bh & 7;
  #pragma unroll
  for (int r = 0; r < 4; r++) {
    float li = __shfl(l_run, qd * 4 + r);
    float inv = 1.0f / li;
    int tok = qb + qd * 4 + r;
    float* ep = ef + (((size_t)(b * Sz + tok)) * NHH + h) * 32;
    ep[n]      = o0[r] * inv;
    ep[16 + n] = o1[r] * inv;
  }
}

// ---------------------------------------------------------------------------
// K3 (MODE 0, verified f32-real output): real-only projection + residual.
// out[t][o] = Re( E[t] . Wo[o] ) + Re(bo[o]) + x_real[t][o]
// Fixes R11's k_proj limits: grid 1024 (4 blocks/CU vs 2), unroll 8 (8
// outstanding WoT loads vs 2), imaginary accumulation dropped (dead work).
// es[] LDS reads are wave-uniform -> broadcast, conflict-free.
// ---------------------------------------------------------------------------
__global__ __launch_bounds__(256) void k_proj_r(const float2* __restrict__ ew,
                                                const float2* __restrict__ WoT,
                                                const void* __restrict__ bo,
                                                const void* __restrict__ xr,
                                                const int* __restrict__ flags,
                                                float* __restrict__ out) {
  __shared__ float2 es[8 * 128];
  bool cbf = flags[0] != 0;
  bool xbf = flags[1] != 0;
  int tid = threadIdx.x;
  int tok0 = (blockIdx.x >> 1) * 8;        // 512 token tiles of 8
  int o = (blockIdx.x & 1) * 256 + tid;    // output half: 0..511
  #pragma unroll
  for (int it = 0; it < 4; it++) {
    int idx = tid + it * 256;
    es[idx] = ew[(size_t)tok0 * 128 + idx];
  }
  __syncthreads();
  float acc[8];
  #pragma unroll
  for (int t = 0; t < 8; t++) acc[t] = 0.f;
  #pragma unroll 8
  for (int j = 0; j < 128; j++) {
    float2 w = WoT[(size_t)j * 512 + o];
    #pragma unroll
    for (int t = 0; t < 8; t++) {
      float2 e = es[t * 128 + j];
      acc[t] = fmaf(e.x, w.x, fmaf(-e.y, w.y, acc[t]));  // real part only
    }
  }
  float bor = ldc(bo, o, cbf).x;
  #pragma unroll
  for (int t = 0; t < 8; t++) {
    size_t gt = tok0 + t;
    out[gt * HIDD + o] = acc[t] + bor + ldr(xr, gt * HIDD + o, xbf);
  }
}

// ---------------------------------------------------------------------------
// K3 (MODE 1 fallback): complex projection, bf16 (im,re) interleaved out.
// ---------------------------------------------------------------------------
__global__ __launch_bounds__(256) void k_proj_c(const float2* __restrict__ ew,
                                                const float2* __restrict__ WoT,
                                                const void* __restrict__ bo,
                                                const void* __restrict__ xr,
                                                const void* __restrict__ xi,
                                                const int* __restrict__ flags,
                                                ushort2* __restrict__ out) {
  __shared__ float2 es[8 * 128];
  bool cbf = flags[0] != 0;
  bool xbf = flags[1] != 0;
  int tid = threadIdx.x;
  int tok0 = blockIdx.x * 8;
  #pragma unroll
  for (int it = 0; it < 4; it++) {
    int idx = tid + it * 256;
    es[idx] = ew[(size_t)tok0 * 128 + idx];
  }
  __syncthreads();
  for (int rep = 0; rep < 2; rep++) {
    int o = tid + rep * 256;
    float2 accT[8];
    #pragma unroll
    for (int t = 0; t < 8; t++) accT[t] = make_float2(0.f, 0.f);
    #pragma unroll 2
    for (int j = 0; j < 128; j++) {
      float2 wv = WoT[(size_t)j * 512 + o];
      #pragma unroll
      for (int t = 0; t < 8; t++) accT[t] = cmadd(accT[t], es[t * 128 + j], wv);
    }
    float2 bov = ldc(bo, o, cbf);
    #pragma unroll
    for (int t = 0; t < 8; t++) {
      size_t gt = tok0 + t;
      float rx = accT[t].x + bov.x + ldr(xr, gt * HIDD + o, xbf);
      float ry = accT[t].y + bov.y + ldr(xi, gt * HIDD + o, xbf);
      out[gt * HIDD + o] = make_ushort2(f2bf(ry), f2bf(rx));
    }
  }
}

// ---------------------------------------------------------------------------
extern "C" void kernel_launch(void* const* d_in, const int* in_sizes, int n_in,
                              void* d_out, int out_size, void* d_ws, size_t ws_size,
                              hipStream_t stream) {
  const void* xr     = d_in[0];
  const void* xi     = d_in[1];
  const void* Wm     = d_in[2];
  const void* bm     = d_in[3];
  const void* Wq     = d_in[4];
  const void* bq     = d_in[5];
  const void* Wk     = d_in[6];
  const void* bk     = d_in[7];
  const void* Wv     = d_in[8];
  const void* bv     = d_in[9];
  const void* metric = d_in[10];
  const void* Wo     = d_in[11];
  const void* bo     = d_in[12];

  float2* W = (float2*)d_ws;
  int* flags = (int*)(W + OFF_FLAG);
  ushort_t* Qb  = (ushort_t*)(W + OFF_QB);
  ushort_t* Kb  = (ushort_t*)(W + OFF_KB);
  ushort_t* VTb = (ushort_t*)(W + OFF_VT);

  k_setup<<<257, 256, 0, stream>>>(metric, (const ushort_t*)xr, Wo, flags,
                                   W + OFF_T, W + OFF_WOT);
  k_qkv<<<dim3(16, 32), 256, 0, stream>>>(xr, xi, Wm, bm, Wq, bq, Wk, bk, Wv, bv,
                                          W + OFF_T, flags, Qb, Kb, VTb);
  k_attn_mf<<<dim3(16, 32), 256, 0, stream>>>(Qb, Kb, VTb, (float*)(W + OFF_E));
  if (out_size == Bz * Sz * HIDD) {
    k_proj_r<<<1024, 256, 0, stream>>>(W + OFF_E, W + OFF_WOT, bo, xr, flags,
                                       (float*)d_out);
  } else {
    k_proj_c<<<512, 256, 0, stream>>>(W + OFF_E, W + OFF_WOT, bo, xr, xi, flags,
                                      (ushort2*)d_out);
  }
}